// Round 4
// baseline (103.968 us; speedup 1.0000x reference)
//
#include <hip/hip_runtime.h>

#define NB   8
#define ND   64
#define NP   1024
#define KDIM 128
#define HID  256
#define OUTD 256
#define CSC  2.885390081777927f   // 2*log2(e)

// a = 2*log2(e)*x  ->  sigr(a) = 1/(1 + e^(2x));  tanh(x) = 1 - 2*sigr
__device__ __forceinline__ float sigr(float a) {
    return __builtin_amdgcn_rcpf(1.0f + __builtin_amdgcn_exp2f(a));
}

// K1: all four projections, pre-scaled by CSC. 16 rows per block.
// blocks [0, 512): protein side (hp, fp). blocks [512, 544): drug side (hd, fd).
__global__ __launch_bounds__(256) void k_proj(
    const float* __restrict__ Xd, const float* __restrict__ Xp,
    const float* __restrict__ Wd, const float* __restrict__ Wa,
    const float* __restrict__ Wp, const float* __restrict__ Wb,
    float* __restrict__ hd, float* __restrict__ fd,
    float* __restrict__ hp, float* __restrict__ fp) {
    int blk = blockIdx.x, t = threadIdx.x;
    const float *X, *W1, *W2;
    float *O1, *O2;
    int row0;
    if (blk < 512) {
        int b = blk >> 6, jt = blk & 63;
        row0 = b * NP + jt * 16; X = Xp; W1 = Wp; W2 = Wb; O1 = hp; O2 = fp;
    } else {
        int r = blk - 512;
        int b = r >> 2, it = r & 3;
        row0 = b * ND + it * 16; X = Xd; W1 = Wd; W2 = Wa; O1 = hd; O2 = fd;
    }
    __shared__ float4 xs[512];          // 16 rows x 128 k = 8 KB
    xs[t]       = ((const float4*)(X + row0 * KDIM))[t];
    xs[t + 256] = ((const float4*)(X + row0 * KDIM))[t + 256];
    __syncthreads();
    float aH[16], aF[16];
#pragma unroll
    for (int r = 0; r < 16; ++r) { aH[r] = 0.f; aF[r] = 0.f; }
    for (int k4 = 0; k4 < 32; ++k4) {
        int k = k4 << 2;
        float w10 = W1[(k + 0) * HID + t], w11 = W1[(k + 1) * HID + t];
        float w12 = W1[(k + 2) * HID + t], w13 = W1[(k + 3) * HID + t];
        float w20 = W2[(k + 0) * HID + t], w21 = W2[(k + 1) * HID + t];
        float w22 = W2[(k + 2) * HID + t], w23 = W2[(k + 3) * HID + t];
#pragma unroll
        for (int r = 0; r < 16; ++r) {
            float4 x = xs[(r << 5) + k4];   // broadcast b128
            aH[r] = fmaf(x.x, w10, aH[r]); aH[r] = fmaf(x.y, w11, aH[r]);
            aH[r] = fmaf(x.z, w12, aH[r]); aH[r] = fmaf(x.w, w13, aH[r]);
            aF[r] = fmaf(x.x, w20, aF[r]); aF[r] = fmaf(x.y, w21, aF[r]);
            aF[r] = fmaf(x.z, w22, aF[r]); aF[r] = fmaf(x.w, w23, aF[r]);
        }
    }
#pragma unroll
    for (int r = 0; r < 16; ++r) {
        O1[(row0 + r) * HID + t] = aH[r] * CSC;
        O2[(row0 + r) * HID + t] = aF[r] * CSC;
    }
}

// K2: shifted scores S[b,i,j] = sum_h (-2 w_h) * sigr(hd'+hp').
// Tile 16 i x 32 j, 2 j per thread. grid = 8 * 4 * 32 = 1024.
// hd read from L2 (512 KB, resident; 4 distinct rows per wave, L1-cached);
// hp in LDS chunk-XOR swizzled; LDS = 33 KB -> 4 blocks/CU.
__global__ __launch_bounds__(256) void k_scores(
    const float* __restrict__ hd, const float* __restrict__ hp,
    const float* __restrict__ wsc, float* __restrict__ S) {
    int blk = blockIdx.x;
    int b = blk >> 7, r = blk & 127, ih = r >> 5, jt = r & 31;
    int t = threadIdx.x;
    __shared__ float4 hps[32 * 64];   // 32 KB, chunk-XOR swizzled
    __shared__ float  w2s[HID];       // 1 KB
    const float4* hpg = (const float4*)(hp + ((b * NP + jt * 32) << 8));
#pragma unroll
    for (int n = 0; n < 8; ++n) {
        int idx = t + (n << 8);
        int row = idx >> 6, ch = idx & 63;
        hps[(row << 6) + (ch ^ (row & 7))] = hpg[idx];
    }
    w2s[t] = -2.0f * wsc[t];
    __syncthreads();

    int jg = t & 15, il = t >> 4;
    const float4* hv4 = (const float4*)(hd + ((b * ND + ih * 16 + il) << 8));
    const float4* p0v = hps + (jg << 6);
    const float4* p1v = hps + ((jg + 16) << 6);
    const float4* w4  = (const float4*)w2s;
    int sw = jg & 7;                  // (jg+16)&7 == jg&7
    float acc0 = 0.f, acc1 = 0.f;
    for (int h4 = 0; h4 < 64; ++h4) {
        float4 hv = hv4[h4];          // global, L1/L2-hit
        float4 wv = w4[h4];
        float4 p0 = p0v[h4 ^ sw];
        float4 p1 = p1v[h4 ^ sw];
        acc0 = fmaf(wv.x, sigr(hv.x + p0.x), acc0);
        acc0 = fmaf(wv.y, sigr(hv.y + p0.y), acc0);
        acc0 = fmaf(wv.z, sigr(hv.z + p0.z), acc0);
        acc0 = fmaf(wv.w, sigr(hv.w + p0.w), acc0);
        acc1 = fmaf(wv.x, sigr(hv.x + p1.x), acc1);
        acc1 = fmaf(wv.y, sigr(hv.y + p1.y), acc1);
        acc1 = fmaf(wv.z, sigr(hv.z + p1.z), acc1);
        acc1 = fmaf(wv.w, sigr(hv.w + p1.w), acc1);
    }
    int i = ih * 16 + il;
    int base = ((b * ND + i) << 10) + jt * 32 + jg;
    S[base]      = acc0;
    S[base + 16] = acc1;
}

// K3: softmax over j per (b,i) row, in place; writes A2 = -2*A.
// No max pass: |S| <= 2*sum|w| <= 32, exp2 arg <= ~46 -> fp32-safe.
__global__ __launch_bounds__(256) void k_softmax(float* __restrict__ S) {
    int row = blockIdx.x;
    int t = threadIdx.x;
    float* Srow = S + (row << 10);
    float4 v = ((float4*)Srow)[t];
    const float L2E = 1.4426950408889634f;
    v.x = __builtin_amdgcn_exp2f(v.x * L2E);
    v.y = __builtin_amdgcn_exp2f(v.y * L2E);
    v.z = __builtin_amdgcn_exp2f(v.z * L2E);
    v.w = __builtin_amdgcn_exp2f(v.w * L2E);
    float s4 = (v.x + v.y) + (v.z + v.w);
#pragma unroll
    for (int off = 32; off > 0; off >>= 1) s4 += __shfl_xor(s4, off, 64);
    __shared__ float wsum[4];
    if ((t & 63) == 0) wsum[t >> 6] = s4;
    __syncthreads();
    float tot = (wsum[0] + wsum[1]) + (wsum[2] + wsum[3]);
    float sneg = -2.0f * __builtin_amdgcn_rcpf(tot);   // A2 = -2*A
    v.x *= sneg; v.y *= sneg; v.z *= sneg; v.w *= sneg;
    ((float4*)Srow)[t] = v;
}

// K4: partial[blk][o] = sum_{i in 32, j in 16} A2 * sigr(fd'+fp').
// (X_int = 64 + sum of all partials, since sum_j A = 1 per i.)
// fd read from L2 (coalesced 1 KB/wave loads); LDS = 6 KB. grid = 1024.
__global__ __launch_bounds__(256) void k_facc(
    const float* __restrict__ fd, const float* __restrict__ fp,
    const float* __restrict__ A2, float* __restrict__ part) {
    int blk = blockIdx.x;
    int b = blk >> 7, rr = blk & 127, ih = rr >> 6, jt = rr & 63;
    int i0 = ih * 32, j0 = jt * 16;
    int t = threadIdx.x;
    __shared__ float4 as4[32 * 4];    // 2 KB  (A2 tile [32 i][16 j])
    __shared__ float4 red[256];       // 4 KB
    if (t < 128) {
        int ii = t >> 2, jq = t & 3;
        as4[t] = ((const float4*)A2)[((b * ND + i0 + ii) << 8) + (j0 >> 2) + jq];
    }
    __syncthreads();

    int o4 = t & 63, jq = t >> 6;
    const float4* fdg = (const float4*)(fd + ((b * ND + i0) << 8));
    const float4* fpg = (const float4*)(fp + ((b * NP + j0 + (jq << 2)) << 8));
    float4 fv0 = fpg[o4], fv1 = fpg[64 + o4], fv2 = fpg[128 + o4], fv3 = fpg[192 + o4];
    float4 acc = {0.f, 0.f, 0.f, 0.f};
    for (int i = 0; i < 32; ++i) {
        float4 dv = fdg[(i << 6) + o4];   // global, coalesced, L2-hit
        float4 a  = as4[(i << 2) + jq];
        acc.x = fmaf(a.x, sigr(dv.x + fv0.x), acc.x);
        acc.y = fmaf(a.x, sigr(dv.y + fv0.y), acc.y);
        acc.z = fmaf(a.x, sigr(dv.z + fv0.z), acc.z);
        acc.w = fmaf(a.x, sigr(dv.w + fv0.w), acc.w);
        acc.x = fmaf(a.y, sigr(dv.x + fv1.x), acc.x);
        acc.y = fmaf(a.y, sigr(dv.y + fv1.y), acc.y);
        acc.z = fmaf(a.y, sigr(dv.z + fv1.z), acc.z);
        acc.w = fmaf(a.y, sigr(dv.w + fv1.w), acc.w);
        acc.x = fmaf(a.z, sigr(dv.x + fv2.x), acc.x);
        acc.y = fmaf(a.z, sigr(dv.y + fv2.y), acc.y);
        acc.z = fmaf(a.z, sigr(dv.z + fv2.z), acc.z);
        acc.w = fmaf(a.z, sigr(dv.w + fv2.w), acc.w);
        acc.x = fmaf(a.w, sigr(dv.x + fv3.x), acc.x);
        acc.y = fmaf(a.w, sigr(dv.y + fv3.y), acc.y);
        acc.z = fmaf(a.w, sigr(dv.z + fv3.z), acc.z);
        acc.w = fmaf(a.w, sigr(dv.w + fv3.w), acc.w);
    }
    red[t] = acc; __syncthreads();
    if (t < 64) {
        float4 r0 = red[t], r1 = red[64 + t], r2 = red[128 + t], r3 = red[192 + t];
        float4 s;
        s.x = (r0.x + r1.x) + (r2.x + r3.x);
        s.y = (r0.y + r1.y) + (r2.y + r3.y);
        s.z = (r0.z + r1.z) + (r2.z + r3.z);
        s.w = (r0.w + r1.w) + (r2.w + r3.w);
        ((float4*)part)[(blk << 6) + t] = s;
    }
}

// K5: out[b][o] = 64 + sum over 128 partials. Deterministic.
__global__ __launch_bounds__(256) void k_reduce(
    const float* __restrict__ part, float* __restrict__ out) {
    int b = blockIdx.x;
    int t = threadIdx.x;
    float s = 64.0f;   // sum_i sum_j A_ij * 1
    for (int q = 0; q < 128; ++q)
        s += part[((b * 128 + q) << 8) + t];
    out[(b << 8) + t] = s;
}

extern "C" void kernel_launch(void* const* d_in, const int* in_sizes, int n_in,
                              void* d_out, int out_size, void* d_ws, size_t ws_size,
                              hipStream_t stream) {
    const float* Xd  = (const float*)d_in[0];
    const float* Xp  = (const float*)d_in[1];
    const float* Wd  = (const float*)d_in[2];
    const float* Wp  = (const float*)d_in[3];
    const float* Wa  = (const float*)d_in[4];
    const float* Wb  = (const float*)d_in[5];
    const float* wsc = (const float*)d_in[6];
    float* out = (float*)d_out;

    float* ws = (float*)d_ws;
    float* hd   = ws;                       // 131072
    float* fd   = hd + NB * ND * HID;       // 131072
    float* hp   = fd + NB * ND * OUTD;      // 2097152
    float* fp   = hp + NB * NP * HID;       // 2097152
    float* S    = fp + NB * NP * OUTD;      // 524288
    float* part = hp;                       // overlay: hp dead after k_scores

    k_proj   <<<544, 256, 0, stream>>>(Xd, Xp, Wd, Wa, Wp, Wb, hd, fd, hp, fp);
    k_scores <<<NB * 128, 256, 0, stream>>>(hd, hp, wsc, S);
    k_softmax<<<NB * ND, 256, 0, stream>>>(S);
    k_facc   <<<NB * 128, 256, 0, stream>>>(fd, fp, S, part);
    k_reduce <<<NB, 256, 0, stream>>>(part, out);
}

// Round 5
// 79.095 us; speedup vs baseline: 1.3145x; 1.3145x over previous
//
#include <hip/hip_runtime.h>

#define NB   8
#define ND   64
#define NP   1024
#define KDIM 128
#define HID  256
#define OUTD 256
#define CSC  2.885390081777927f   // 2*log2(e)

// E-trick: store E = exp2(CSC*proj) = e^{2*proj}. Then
// sigma(2(xd+xp)) = 1/(1 + Ed*Ep) = rcp(fma(Ed,Ep,1)) -> no exp in inner loops.
// tanh(xd+xp) = 1 - 2*sigma.

// K1: projections + exp2. Block: 8 rows x 128 h-cols x both output matrices.
// blocks [0,2048): protein side; [2048,2176): drug side.
__global__ __launch_bounds__(256) void k_proj(
    const float* __restrict__ Xd, const float* __restrict__ Xp,
    const float* __restrict__ Wd, const float* __restrict__ Wa,
    const float* __restrict__ Wp, const float* __restrict__ Wb,
    float* __restrict__ Ehd, float* __restrict__ Efd,
    float* __restrict__ Ehp, float* __restrict__ Efp) {
    int blk = blockIdx.x, t = threadIdx.x;
    const float *X, *W1, *W2;
    float *O1, *O2;
    int row0, half;
    if (blk < 2048) {
        int rb = blk >> 1; half = blk & 1;
        int b = rb >> 7, jt = rb & 127;
        row0 = b * NP + jt * 8; X = Xp; W1 = Wp; W2 = Wb; O1 = Ehp; O2 = Efp;
    } else {
        int r = blk - 2048;
        int rb = r >> 1; half = r & 1;
        int b = rb >> 3, it = rb & 7;
        row0 = b * ND + it * 8; X = Xd; W1 = Wd; W2 = Wa; O1 = Ehd; O2 = Efd;
    }
    int os = t >> 7, hl = t & 127;      // os is wave-uniform (waves 0-1 vs 2-3)
    int h = (half << 7) + hl;
    const float* W = os ? W2 : W1;
    float* O = os ? O2 : O1;
    __shared__ float4 xs[256];          // 8 rows x 128 k = 4 KB
    xs[t] = ((const float4*)(X + row0 * KDIM))[t];
    __syncthreads();
    float acc[8];
#pragma unroll
    for (int r = 0; r < 8; ++r) acc[r] = 0.f;
    for (int k4 = 0; k4 < 32; ++k4) {
        int k = k4 << 2;
        float w0 = W[(k + 0) * HID + h], w1 = W[(k + 1) * HID + h];
        float w2 = W[(k + 2) * HID + h], w3 = W[(k + 3) * HID + h];
#pragma unroll
        for (int r = 0; r < 8; ++r) {
            float4 x = xs[(r << 5) + k4];   // LDS b128 broadcast
            acc[r] = fmaf(x.x, w0, acc[r]);
            acc[r] = fmaf(x.y, w1, acc[r]);
            acc[r] = fmaf(x.z, w2, acc[r]);
            acc[r] = fmaf(x.w, w3, acc[r]);
        }
    }
#pragma unroll
    for (int r = 0; r < 8; ++r)
        O[(row0 + r) * HID + h] = __builtin_amdgcn_exp2f(acc[r] * CSC);
}

// K2: shifted scores S[b,i,j] = sum_h (-2 w_h) * rcp(1 + Ehd*Ehp).
// Tile 16 i x 32 j, 2 j per thread. grid = 1024. Ehd from L2; Ehp in
// chunk-XOR-swizzled LDS. LDS = 33 KB -> 4 blocks/CU.
__global__ __launch_bounds__(256) void k_scores(
    const float* __restrict__ Ehd, const float* __restrict__ Ehp,
    const float* __restrict__ wsc, float* __restrict__ S) {
    int blk = blockIdx.x;
    int b = blk >> 7, r = blk & 127, ih = r >> 5, jt = r & 31;
    int t = threadIdx.x;
    __shared__ float4 hps[32 * 64];   // 32 KB, chunk-XOR swizzled
    __shared__ float  w2s[HID];       // 1 KB
    const float4* hpg = (const float4*)(Ehp + ((b * NP + jt * 32) << 8));
#pragma unroll
    for (int n = 0; n < 8; ++n) {
        int idx = t + (n << 8);
        int row = idx >> 6, ch = idx & 63;
        hps[(row << 6) + (ch ^ (row & 7))] = hpg[idx];
    }
    w2s[t] = -2.0f * wsc[t];
    __syncthreads();

    int jg = t & 15, il = t >> 4;
    const float4* hv4 = (const float4*)(Ehd + ((b * ND + ih * 16 + il) << 8));
    const float4* p0v = hps + (jg << 6);
    const float4* p1v = hps + ((jg + 16) << 6);
    const float4* w4  = (const float4*)w2s;
    int sw = jg & 7;                  // (jg+16)&7 == jg&7
    float acc0 = 0.f, acc1 = 0.f;
    for (int h4 = 0; h4 < 64; ++h4) {
        float4 hv = hv4[h4];          // global, L1/L2-hit
        float4 wv = w4[h4];
        float4 p0 = p0v[h4 ^ sw];
        float4 p1 = p1v[h4 ^ sw];
        acc0 = fmaf(wv.x, __builtin_amdgcn_rcpf(fmaf(hv.x, p0.x, 1.f)), acc0);
        acc0 = fmaf(wv.y, __builtin_amdgcn_rcpf(fmaf(hv.y, p0.y, 1.f)), acc0);
        acc0 = fmaf(wv.z, __builtin_amdgcn_rcpf(fmaf(hv.z, p0.z, 1.f)), acc0);
        acc0 = fmaf(wv.w, __builtin_amdgcn_rcpf(fmaf(hv.w, p0.w, 1.f)), acc0);
        acc1 = fmaf(wv.x, __builtin_amdgcn_rcpf(fmaf(hv.x, p1.x, 1.f)), acc1);
        acc1 = fmaf(wv.y, __builtin_amdgcn_rcpf(fmaf(hv.y, p1.y, 1.f)), acc1);
        acc1 = fmaf(wv.z, __builtin_amdgcn_rcpf(fmaf(hv.z, p1.z, 1.f)), acc1);
        acc1 = fmaf(wv.w, __builtin_amdgcn_rcpf(fmaf(hv.w, p1.w, 1.f)), acc1);
    }
    int i = ih * 16 + il;
    int base = ((b * ND + i) << 10) + jt * 32 + jg;
    S[base]      = acc0;
    S[base + 16] = acc1;
}

// K3: softmax over j per (b,i) row, in place; writes A2 = -2*A.
// No max pass: |S| <= 2*sum|w| <= 32, exp2 arg <= ~46 -> fp32-safe.
__global__ __launch_bounds__(256) void k_softmax(float* __restrict__ S) {
    int row = blockIdx.x;
    int t = threadIdx.x;
    float* Srow = S + (row << 10);
    float4 v = ((float4*)Srow)[t];
    const float L2E = 1.4426950408889634f;
    v.x = __builtin_amdgcn_exp2f(v.x * L2E);
    v.y = __builtin_amdgcn_exp2f(v.y * L2E);
    v.z = __builtin_amdgcn_exp2f(v.z * L2E);
    v.w = __builtin_amdgcn_exp2f(v.w * L2E);
    float s4 = (v.x + v.y) + (v.z + v.w);
#pragma unroll
    for (int off = 32; off > 0; off >>= 1) s4 += __shfl_xor(s4, off, 64);
    __shared__ float wsum[4];
    if ((t & 63) == 0) wsum[t >> 6] = s4;
    __syncthreads();
    float tot = (wsum[0] + wsum[1]) + (wsum[2] + wsum[3]);
    float sneg = -2.0f * __builtin_amdgcn_rcpf(tot);   // A2 = -2*A
    v.x *= sneg; v.y *= sneg; v.z *= sneg; v.w *= sneg;
    ((float4*)Srow)[t] = v;
}

// K4: partial[blk][o] = sum_{i in 32, j in 16} A2 * rcp(1 + Efd*Efp).
// (X_int = 64 + sum of all partials, since sum_j A = 1 per i.)
// Efd from L2 (coalesced 1 KB/wave loads); LDS = 6 KB. grid = 1024.
__global__ __launch_bounds__(256) void k_facc(
    const float* __restrict__ Efd, const float* __restrict__ Efp,
    const float* __restrict__ A2, float* __restrict__ part) {
    int blk = blockIdx.x;
    int b = blk >> 7, rr = blk & 127, ih = rr >> 6, jt = rr & 63;
    int i0 = ih * 32, j0 = jt * 16;
    int t = threadIdx.x;
    __shared__ float4 as4[32 * 4];    // 2 KB  (A2 tile [32 i][16 j])
    __shared__ float4 red[256];       // 4 KB
    if (t < 128) {
        int ii = t >> 2, jq = t & 3;
        as4[t] = ((const float4*)A2)[((b * ND + i0 + ii) << 8) + (j0 >> 2) + jq];
    }
    __syncthreads();

    int o4 = t & 63, jq = t >> 6;
    const float4* fdg = (const float4*)(Efd + ((b * ND + i0) << 8));
    const float4* fpg = (const float4*)(Efp + ((b * NP + j0 + (jq << 2)) << 8));
    float4 fv0 = fpg[o4], fv1 = fpg[64 + o4], fv2 = fpg[128 + o4], fv3 = fpg[192 + o4];
    float4 acc = {0.f, 0.f, 0.f, 0.f};
    for (int i = 0; i < 32; ++i) {
        float4 dv = fdg[(i << 6) + o4];   // global, coalesced, L2-hit
        float4 a  = as4[(i << 2) + jq];
        acc.x = fmaf(a.x, __builtin_amdgcn_rcpf(fmaf(dv.x, fv0.x, 1.f)), acc.x);
        acc.y = fmaf(a.x, __builtin_amdgcn_rcpf(fmaf(dv.y, fv0.y, 1.f)), acc.y);
        acc.z = fmaf(a.x, __builtin_amdgcn_rcpf(fmaf(dv.z, fv0.z, 1.f)), acc.z);
        acc.w = fmaf(a.x, __builtin_amdgcn_rcpf(fmaf(dv.w, fv0.w, 1.f)), acc.w);
        acc.x = fmaf(a.y, __builtin_amdgcn_rcpf(fmaf(dv.x, fv1.x, 1.f)), acc.x);
        acc.y = fmaf(a.y, __builtin_amdgcn_rcpf(fmaf(dv.y, fv1.y, 1.f)), acc.y);
        acc.z = fmaf(a.y, __builtin_amdgcn_rcpf(fmaf(dv.z, fv1.z, 1.f)), acc.z);
        acc.w = fmaf(a.y, __builtin_amdgcn_rcpf(fmaf(dv.w, fv1.w, 1.f)), acc.w);
        acc.x = fmaf(a.z, __builtin_amdgcn_rcpf(fmaf(dv.x, fv2.x, 1.f)), acc.x);
        acc.y = fmaf(a.z, __builtin_amdgcn_rcpf(fmaf(dv.y, fv2.y, 1.f)), acc.y);
        acc.z = fmaf(a.z, __builtin_amdgcn_rcpf(fmaf(dv.z, fv2.z, 1.f)), acc.z);
        acc.w = fmaf(a.z, __builtin_amdgcn_rcpf(fmaf(dv.w, fv2.w, 1.f)), acc.w);
        acc.x = fmaf(a.w, __builtin_amdgcn_rcpf(fmaf(dv.x, fv3.x, 1.f)), acc.x);
        acc.y = fmaf(a.w, __builtin_amdgcn_rcpf(fmaf(dv.y, fv3.y, 1.f)), acc.y);
        acc.z = fmaf(a.w, __builtin_amdgcn_rcpf(fmaf(dv.z, fv3.z, 1.f)), acc.z);
        acc.w = fmaf(a.w, __builtin_amdgcn_rcpf(fmaf(dv.w, fv3.w, 1.f)), acc.w);
    }
    red[t] = acc; __syncthreads();
    if (t < 64) {
        float4 r0 = red[t], r1 = red[64 + t], r2 = red[128 + t], r3 = red[192 + t];
        float4 s;
        s.x = (r0.x + r1.x) + (r2.x + r3.x);
        s.y = (r0.y + r1.y) + (r2.y + r3.y);
        s.z = (r0.z + r1.z) + (r2.z + r3.z);
        s.w = (r0.w + r1.w) + (r2.w + r3.w);
        ((float4*)part)[(blk << 6) + t] = s;
    }
}

// K5: out[b][o] = 64 + sum over 128 partials. Deterministic.
__global__ __launch_bounds__(256) void k_reduce(
    const float* __restrict__ part, float* __restrict__ out) {
    int b = blockIdx.x;
    int t = threadIdx.x;
    float s = 64.0f;   // sum_i sum_j A_ij * 1
    for (int q = 0; q < 128; ++q)
        s += part[((b * 128 + q) << 8) + t];
    out[(b << 8) + t] = s;
}

extern "C" void kernel_launch(void* const* d_in, const int* in_sizes, int n_in,
                              void* d_out, int out_size, void* d_ws, size_t ws_size,
                              hipStream_t stream) {
    const float* Xd  = (const float*)d_in[0];
    const float* Xp  = (const float*)d_in[1];
    const float* Wd  = (const float*)d_in[2];
    const float* Wp  = (const float*)d_in[3];
    const float* Wa  = (const float*)d_in[4];
    const float* Wb  = (const float*)d_in[5];
    const float* wsc = (const float*)d_in[6];
    float* out = (float*)d_out;

    float* ws = (float*)d_ws;
    float* Ehd  = ws;                       // 131072
    float* Efd  = Ehd + NB * ND * HID;      // 131072
    float* Ehp  = Efd + NB * ND * OUTD;     // 2097152
    float* Efp  = Ehp + NB * NP * HID;      // 2097152
    float* S    = Efp + NB * NP * OUTD;     // 524288
    float* part = Ehp;                      // overlay: Ehp dead after k_scores

    k_proj   <<<2176, 256, 0, stream>>>(Xd, Xp, Wd, Wa, Wp, Wb, Ehd, Efd, Ehp, Efp);
    k_scores <<<NB * 128, 256, 0, stream>>>(Ehd, Ehp, wsc, S);
    k_softmax<<<NB * ND, 256, 0, stream>>>(S);
    k_facc   <<<NB * 128, 256, 0, stream>>>(Efd, Efp, S, part);
    k_reduce <<<NB, 256, 0, stream>>>(part, out);
}